// Round 2
// baseline (776.563 us; speedup 1.0000x reference)
//
#include <hip/hip_runtime.h>

#define N_NODES 50000
#define N_PAD   50048          // 391 * 128
#define N_EDGES 800000
#define N_REL   8
#define NSEG    (N_REL * N_NODES)      // 400000
#define SCAN_NB 391                    // ceil(NSEG / 1024)
#define NSTRIPE 391                    // 128-row stripes
#define SPX     49                     // ceil(391/8) stripes per XCD

typedef short bf16x8 __attribute__((ext_vector_type(8)));
typedef float f32x4  __attribute__((ext_vector_type(4)));

__device__ __forceinline__ ushort f2bf(float f) {
    union { float f; unsigned u; } c; c.f = f;
    unsigned u = c.u + 0x7fffu + ((c.u >> 16) & 1u);   // RNE
    return (ushort)(u >> 16);
}
__device__ __forceinline__ void add8(float* s, uint4 v) {
    unsigned u[4] = {v.x, v.y, v.z, v.w};
    #pragma unroll
    for (int k = 0; k < 4; ++k) {
        s[2 * k]     += __uint_as_float(u[k] << 16);
        s[2 * k + 1] += __uint_as_float(u[k] & 0xffff0000u);
    }
}
__device__ __forceinline__ void fma8(float* s, uint4 v, float w) {
    unsigned u[4] = {v.x, v.y, v.z, v.w};
    #pragma unroll
    for (int k = 0; k < 4; ++k) {
        s[2 * k]     = fmaf(__uint_as_float(u[k] << 16),        w, s[2 * k]);
        s[2 * k + 1] = fmaf(__uint_as_float(u[k] & 0xffff0000u), w, s[2 * k + 1]);
    }
}
__device__ __forceinline__ void async16(const ushort* g, ushort* l) {
    __builtin_amdgcn_global_load_lds((const __attribute__((address_space(1))) void*)g,
                                     (__attribute__((address_space(3))) void*)l, 16, 0, 0);
}

// ---------------- edge preprocessing: counting sort by (dst*R + rel) ----------------
// dst-major key: each dst owns ONE contiguous run of ~16 edges -> gather is a single
// flat loop with high MLP instead of 8 trip-2 loops with serial dependent loads.
// sorted[pos] packs {src:17b | rel:3b | segment_count:12b} in one int (4 B/edge keeps
// the workspace footprint BELOW the proven round-0 layout; count<=4095 holds trivially
// for the Poisson(2) in-degrees of this fixed input).

__global__ void count_edges(const int* __restrict__ dst, const int* __restrict__ et,
                            int* __restrict__ cnt) {
    int e = blockIdx.x * 256 + threadIdx.x;
    if (e < N_EDGES) atomicAdd(&cnt[dst[e] * N_REL + et[e]], 1);
}

__global__ __launch_bounds__(256) void scan_pass1(const int* __restrict__ cnt,
                                                  int* __restrict__ sums) {
    __shared__ int sc[256];
    int b = blockIdx.x, t = threadIdx.x;
    int base = b * 1024 + t * 4;
    int v = 0;
    #pragma unroll
    for (int i = 0; i < 4; ++i) { int idx = base + i; if (idx < NSEG) v += cnt[idx]; }
    sc[t] = v; __syncthreads();
    for (int off = 1; off < 256; off <<= 1) {
        int x = (t >= off) ? sc[t - off] : 0;
        __syncthreads(); sc[t] += x; __syncthreads();
    }
    if (t == 255) sums[b] = sc[255];
}

__global__ __launch_bounds__(512) void scan_pass2(int* __restrict__ sums, int nb) {
    __shared__ int sc[512];
    int t = threadIdx.x;
    int v = (t < nb) ? sums[t] : 0;
    sc[t] = v; __syncthreads();
    for (int off = 1; off < 512; off <<= 1) {
        int x = (t >= off) ? sc[t - off] : 0;
        __syncthreads(); sc[t] += x; __syncthreads();
    }
    if (t < nb) sums[t] = sc[t] - v;     // exclusive
}

__global__ __launch_bounds__(256) void scan_pass3(const int* __restrict__ cnt,
                                                  const int* __restrict__ sums,
                                                  int* __restrict__ row_ptr) {
    __shared__ int sc[256];
    int b = blockIdx.x, t = threadIdx.x;
    int base = b * 1024 + t * 4;
    int e[4]; int v = 0;
    #pragma unroll
    for (int i = 0; i < 4; ++i) { int idx = base + i; e[i] = (idx < NSEG) ? cnt[idx] : 0; v += e[i]; }
    sc[t] = v; __syncthreads();
    for (int off = 1; off < 256; off <<= 1) {
        int x = (t >= off) ? sc[t - off] : 0;
        __syncthreads(); sc[t] += x; __syncthreads();
    }
    int run = sums[b] + (sc[t] - v);
    #pragma unroll
    for (int i = 0; i < 4; ++i) {
        int idx = base + i;
        if (idx < NSEG) row_ptr[idx] = run;
        run += e[i];
    }
    if (b == 0 && t == 0) row_ptr[NSEG] = N_EDGES;
}

// cnt doubles as the placement cursor (atomicSub); cnt is dead afterwards.
__global__ void place_edges(const int* __restrict__ src, const int* __restrict__ dst,
                            const int* __restrict__ et, const int* __restrict__ row_ptr,
                            int* __restrict__ cnt, int* __restrict__ sorted) {
    int e = blockIdx.x * 256 + threadIdx.x;
    if (e >= N_EDGES) return;
    int r = et[e];
    int key = dst[e] * N_REL + r;
    int old = atomicSub(&cnt[key], 1);
    int r0 = row_ptr[key];
    int c = row_ptr[key + 1] - r0;                 // |N_r(dst)| for this segment
    sorted[r0 + old - 1] = src[e] | (r << 17) | (c << 20);
}

// ---------------- weight pack: BT[col][k] bf16, col = r*O+o (r=8 -> root), zero-pad cols ----------------

__global__ void convert_weights(const float* __restrict__ W, const float* __restrict__ root,
                                ushort* __restrict__ BT, int K, int O, int NPAD) {
    int idx = blockIdx.x * 256 + threadIdx.x;
    if (idx >= NPAD * K) return;
    int col = idx / K, i = idx % K;
    float v = 0.0f;
    if (col < N_REL * O) {
        int r = col / O, o = col % O;
        v = W[((size_t)r * K + i) * O + o];
    } else if (col < (N_REL + 1) * O) {
        v = root[(size_t)i * O + (col - N_REL * O)];
    }
    BT[idx] = f2bf(v);
}

__global__ void f32_to_bf16(const float* __restrict__ in, ushort* __restrict__ out, int n4) {
    int i = blockIdx.x * 256 + threadIdx.x;
    if (i >= n4) return;
    float4 v = ((const float4*)in)[i];
    ushort4 s; s.x = f2bf(v.x); s.y = f2bf(v.y); s.z = f2bf(v.z); s.w = f2bf(v.w);
    ((ushort4*)out)[i] = s;
}

// ---------------- bf16 MFMA GEMM (XCD-pinned swizzle, swapped-operand direct-store epilogue) ----------------
// Swapped MFMA: acc[i][j] = mfma(b[j], a[i], acc). A/B fragment layouts of
// mfma_f32_16x16x32_bf16 are symmetric (same trick as HK's swapped QK^T), so the
// lane (l16,q), reg r holds Y[row = wm+i*16+l16][col = wn+j*16+q*4+r]: 4 CONSECUTIVE
// cols. Pack to 8B, store straight to global (32B-contiguous per row; L2 merges to
// full lines). Removes the two-pass LDS transpose: -64 ds_write_b16/thread (the 8.1M
// bank-conflict cycles), -8 ds_read_b128, -1 barrier.
template<int K, int CTS, int NW>
__global__ __launch_bounds__(256)
void gemm_mfma(const ushort* __restrict__ A, const ushort* __restrict__ BT,
               ushort* __restrict__ Y) {
    // ---- swizzle: f -> (stripe y, col-tile ct) pinned to XCD f&7 ----
    const int f = blockIdx.x;
    const int g = f & 7, m = f >> 3;
    const int y = g + 8 * (m / CTS);
    const int ct = m % CTS;
    if (y >= NSTRIPE) return;               // uniform early-exit (before any barrier)
    const int row0 = y * 128;
    const int col0 = ct * 128;

    __shared__ ushort SMEM[8192];           // 16 KB: As|Bs only (no epilogue buffer)
    ushort* As = SMEM;                      // 128*32 = 4096 ushorts
    ushort* Bs = SMEM + 4096;
    const int t = threadIdx.x;
    const int lane = t & 63;
    const int w = t >> 6;
    const int l16 = lane & 15, q = lane >> 4;
    const int wm = (w & 1) * 64, wn = (w >> 1) * 64;

    // staging: chunk c (0..511) = 16B; row = c>>2, kcol = (c&3)*8. Wave w handles
    // chunks [w*64, w*64+64) and [(w+4)*64, ...): LDS dst = wave-uniform base + lane*16.
    const int c0i = w * 64 + lane;
    const int c1i = c0i + 256;
    const size_t ga0 = (size_t)(c0i >> 2) * K + (size_t)(c0i & 3) * 8;
    const size_t ga1 = (size_t)(c1i >> 2) * K + (size_t)(c1i & 3) * 8;
    const ushort* Ab = A + (size_t)row0 * K;
    const ushort* Bb = BT + (size_t)col0 * K;
    ushort* lA0 = &As[w * 512];
    ushort* lA1 = &As[(w + 4) * 512];
    ushort* lB0 = &Bs[w * 512];
    ushort* lB1 = &Bs[(w + 4) * 512];

    f32x4 acc[4][4] = {};

    #pragma unroll
    for (int k0 = 0; k0 < K; k0 += 32) {
        __syncthreads();                    // previous iter's LDS reads done
        async16(Ab + k0 + ga0, lA0);
        async16(Ab + k0 + ga1, lA1);
        async16(Bb + k0 + ga0, lB0);
        async16(Bb + k0 + ga1, lB1);
        __syncthreads();                    // drains global_load_lds (vmcnt 0)
        bf16x8 a[4], b[4];
        #pragma unroll
        for (int i = 0; i < 4; ++i) {
            a[i] = *(const bf16x8*)&As[(wm + i * 16 + l16) * 32 + q * 8];
            b[i] = *(const bf16x8*)&Bs[(wn + i * 16 + l16) * 32 + q * 8];
        }
        #pragma unroll
        for (int i = 0; i < 4; ++i)
            #pragma unroll
            for (int j = 0; j < 4; ++j)
                acc[i][j] = __builtin_amdgcn_mfma_f32_16x16x32_bf16(b[j], a[i], acc[i][j], 0, 0, 0);
    }

    // ---- epilogue: direct packed stores, no LDS, no barrier ----
    #pragma unroll
    for (int i = 0; i < 4; ++i) {
        const size_t rbase = (size_t)(row0 + wm + i * 16 + l16) * NW + col0 + wn + q * 4;
        #pragma unroll
        for (int j = 0; j < 4; ++j) {
            uint2 v;
            v.x = (unsigned)f2bf(acc[i][j][0]) | ((unsigned)f2bf(acc[i][j][1]) << 16);
            v.y = (unsigned)f2bf(acc[i][j][2]) | ((unsigned)f2bf(acc[i][j][3]) << 16);
            *(uint2*)(Y + rbase + j * 16) = v;
        }
    }
}

// ---------------- fused gather: out[d] = act( root + bias + sum_e w_e * Y[src_e, rel_e*O+c] ) ----------------
// dst-major sort: one contiguous edge run per dst; weight = 1/count decoded from the
// packed entry. 4-unrolled flat loop -> 4 independent metadata loads + 4 independent
// Y loads in flight (vs round-0's 8 trip-2 loops with a serial dependent chain).
template<int O>
__global__ __launch_bounds__(256)
void gather_kernel(const ushort* __restrict__ Y, int NW,
                   const int* __restrict__ row_ptr, const int* __restrict__ sorted,
                   const float* __restrict__ bias,
                   float* __restrict__ out_f32, ushort* __restrict__ out_bf16, int relu) {
    constexpr int TPN = O / 8;
    int d = blockIdx.x * (256 / TPN) + threadIdx.x / TPN;
    if (d >= N_NODES) return;
    int c0 = (threadIdx.x % TPN) * 8;
    int p0 = row_ptr[d * N_REL];
    int p1 = row_ptr[d * N_REL + N_REL];
    float sum[8] = {};
    add8(sum, *(const uint4*)(Y + (size_t)d * NW + N_REL * O + c0));   // root slice
    #pragma unroll
    for (int k = 0; k < 8; ++k) sum[k] += bias[c0 + k];
    const ushort* Yc = Y + c0;
    #define EDGE_LD(sx) (*(const uint4*)(Yc + (size_t)((sx) & 0x1FFFF) * NW + ((((sx) >> 17) & 7) * O)))
    #define EDGE_W(sx)  (1.0f / (float)((unsigned)(sx) >> 20))
    int e = p0;
    for (; e + 4 <= p1; e += 4) {
        int s0 = sorted[e], s1 = sorted[e + 1], s2 = sorted[e + 2], s3 = sorted[e + 3];
        uint4 v0 = EDGE_LD(s0);
        uint4 v1 = EDGE_LD(s1);
        uint4 v2 = EDGE_LD(s2);
        uint4 v3 = EDGE_LD(s3);
        fma8(sum, v0, EDGE_W(s0));
        fma8(sum, v1, EDGE_W(s1));
        fma8(sum, v2, EDGE_W(s2));
        fma8(sum, v3, EDGE_W(s3));
    }
    for (; e < p1; ++e) {
        int s = sorted[e];
        uint4 v = EDGE_LD(s);
        fma8(sum, v, EDGE_W(s));
    }
    #undef EDGE_LD
    #undef EDGE_W
    if (relu) {
        #pragma unroll
        for (int k = 0; k < 8; ++k) sum[k] = fmaxf(sum[k], 0.0f);
    }
    if (out_bf16) {
        ushort o[8];
        #pragma unroll
        for (int k = 0; k < 8; ++k) o[k] = f2bf(sum[k]);
        *(uint4*)(out_bf16 + (size_t)d * O + c0) = *(const uint4*)o;
    } else {
        float* p = out_f32 + (size_t)d * O + c0;
        *(float4*)p = make_float4(sum[0], sum[1], sum[2], sum[3]);
        *(float4*)(p + 4) = make_float4(sum[4], sum[5], sum[6], sum[7]);
    }
}

// ---------------- host side ----------------

extern "C" void kernel_launch(void* const* d_in, const int* in_sizes, int n_in,
                              void* d_out, int out_size, void* d_ws, size_t ws_size,
                              hipStream_t stream) {
    const float* x  = (const float*)d_in[0];
    const int*   ei = (const int*)d_in[1];
    const int*   et = (const int*)d_in[2];
    const float* W[4]  = {(const float*)d_in[3], (const float*)d_in[6], (const float*)d_in[9],  (const float*)d_in[12]};
    const float* RT[4] = {(const float*)d_in[4], (const float*)d_in[7], (const float*)d_in[10], (const float*)d_in[13]};
    const float* BI[4] = {(const float*)d_in[5], (const float*)d_in[8], (const float*)d_in[11], (const float*)d_in[14]};
    const int KS[4] = {128, 256, 256, 256};
    const int NP[4] = {2304, 2304, 2304, 640};   // packed+padded BT rows (= Y width)
    const int* src = ei;
    const int* dst = ei + N_EDGES;

    // ---- workspace carve-up (footprint <= proven round-0 layout: 264.3 MB) ----
    char* ws = (char*)d_ws;
    size_t off = 0;
    auto take = [&](size_t bytes) -> char* {
        char* p = ws + off;
        off = (off + bytes + 255) & ~(size_t)255;
        return p;
    };
    int* row_ptr    = (int*)take((size_t)(NSEG + 1) * 4);
    int* sorted     = (int*)take((size_t)N_EDGES * 4);
    ushort* BTp[4];
    for (int l = 0; l < 4; ++l) BTp[l] = (ushort*)take((size_t)NP[l] * KS[l] * 2);
    ushort* hb = (ushort*)take((size_t)N_PAD * 256 * 2);
    ushort* Yb = (ushort*)take((size_t)N_PAD * 2304 * 2);
    // cnt + sums alias the head of Yb: dead before the first GEMM writes Yb
    // (strict stream order), saves their 1.6 MB from the footprint.
    int* cnt  = (int*)Yb;
    int* sums = (int*)((char*)Yb + (size_t)NSEG * 4);

    // ---- edge preprocessing (once per call) ----
    hipMemsetAsync(cnt, 0, (size_t)NSEG * 4, stream);
    count_edges<<<(N_EDGES + 255) / 256, 256, 0, stream>>>(dst, et, cnt);
    scan_pass1<<<SCAN_NB, 256, 0, stream>>>(cnt, sums);
    scan_pass2<<<1, 512, 0, stream>>>(sums, SCAN_NB);
    scan_pass3<<<SCAN_NB, 256, 0, stream>>>(cnt, sums, row_ptr);
    place_edges<<<(N_EDGES + 255) / 256, 256, 0, stream>>>(src, dst, et, row_ptr, cnt, sorted);

    // ---- weight pack ----
    for (int l = 0; l < 4; ++l) {
        int n = NP[l] * KS[l];
        convert_weights<<<(n + 255) / 256, 256, 0, stream>>>(W[l], RT[l], BTp[l], KS[l],
                                                             l == 3 ? 64 : 256, NP[l]);
    }

    // ---- input to bf16 ----
    f32_to_bf16<<<(N_NODES * 128 / 4 + 255) / 256, 256, 0, stream>>>(x, hb, N_NODES * 128 / 4);

    // ---- 4 layers: XCD-swizzled GEMM + fused gather ----
    const int G18 = 8 * SPX * 18;   // 7056
    const int G5  = 8 * SPX * 5;    // 1960
    gemm_mfma<128, 18, 2304><<<G18, 256, 0, stream>>>(hb, BTp[0], Yb);
    gather_kernel<256><<<dim3((N_NODES + 7) / 8), 256, 0, stream>>>(
        Yb, 2304, row_ptr, sorted, BI[0], nullptr, hb, 1);

    gemm_mfma<256, 18, 2304><<<G18, 256, 0, stream>>>(hb, BTp[1], Yb);
    gather_kernel<256><<<dim3((N_NODES + 7) / 8), 256, 0, stream>>>(
        Yb, 2304, row_ptr, sorted, BI[1], nullptr, hb, 1);

    gemm_mfma<256, 18, 2304><<<G18, 256, 0, stream>>>(hb, BTp[2], Yb);
    gather_kernel<256><<<dim3((N_NODES + 7) / 8), 256, 0, stream>>>(
        Yb, 2304, row_ptr, sorted, BI[2], nullptr, hb, 1);

    gemm_mfma<256, 5, 640><<<G5, 256, 0, stream>>>(hb, BTp[3], Yb);
    gather_kernel<64><<<dim3((N_NODES + 31) / 32), 256, 0, stream>>>(
        Yb, 640, row_ptr, sorted, BI[3], (float*)d_out, nullptr, 0);
}

// Round 3
// 670.989 us; speedup vs baseline: 1.1573x; 1.1573x over previous
//
#include <hip/hip_runtime.h>

#define N_NODES 50000
#define N_PAD   50048          // 391 * 128
#define N_EDGES 800000
#define N_REL   8
#define NSEG    (N_REL * N_NODES)      // 400000
#define SCAN_NB 391                    // ceil(NSEG / 1024)
#define NSTRIPE 391                    // 128-row stripes
#define SPX     49                     // ceil(391/8) stripes per XCD

typedef short bf16x8 __attribute__((ext_vector_type(8)));
typedef float f32x4  __attribute__((ext_vector_type(4)));

__device__ __forceinline__ ushort f2bf(float f) {
    union { float f; unsigned u; } c; c.f = f;
    unsigned u = c.u + 0x7fffu + ((c.u >> 16) & 1u);   // RNE
    return (ushort)(u >> 16);
}
__device__ __forceinline__ void add8(float* s, uint4 v) {
    unsigned u[4] = {v.x, v.y, v.z, v.w};
    #pragma unroll
    for (int k = 0; k < 4; ++k) {
        s[2 * k]     += __uint_as_float(u[k] << 16);
        s[2 * k + 1] += __uint_as_float(u[k] & 0xffff0000u);
    }
}
__device__ __forceinline__ void fma8(float* s, uint4 v, float w) {
    unsigned u[4] = {v.x, v.y, v.z, v.w};
    #pragma unroll
    for (int k = 0; k < 4; ++k) {
        s[2 * k]     = fmaf(__uint_as_float(u[k] << 16),        w, s[2 * k]);
        s[2 * k + 1] = fmaf(__uint_as_float(u[k] & 0xffff0000u), w, s[2 * k + 1]);
    }
}
__device__ __forceinline__ void async16(const ushort* g, ushort* l) {
    __builtin_amdgcn_global_load_lds((const __attribute__((address_space(1))) void*)g,
                                     (__attribute__((address_space(3))) void*)l, 16, 0, 0);
}

// ---------------- edge preprocessing: counting sort by (dst*R + rel) ----------------
// dst-major key: each dst owns ONE contiguous run of ~16 edges -> gather is a single
// flat loop with high MLP instead of 8 trip-2 loops with serial dependent loads.
// sorted[pos] packs {src:17b | rel:3b | segment_count:12b} in one int (4 B/edge).

__global__ void count_edges(const int* __restrict__ dst, const int* __restrict__ et,
                            int* __restrict__ cnt) {
    int e = blockIdx.x * 256 + threadIdx.x;
    if (e < N_EDGES) atomicAdd(&cnt[dst[e] * N_REL + et[e]], 1);
}

__global__ __launch_bounds__(256) void scan_pass1(const int* __restrict__ cnt,
                                                  int* __restrict__ sums) {
    __shared__ int sc[256];
    int b = blockIdx.x, t = threadIdx.x;
    int base = b * 1024 + t * 4;
    int v = 0;
    #pragma unroll
    for (int i = 0; i < 4; ++i) { int idx = base + i; if (idx < NSEG) v += cnt[idx]; }
    sc[t] = v; __syncthreads();
    for (int off = 1; off < 256; off <<= 1) {
        int x = (t >= off) ? sc[t - off] : 0;
        __syncthreads(); sc[t] += x; __syncthreads();
    }
    if (t == 255) sums[b] = sc[255];
}

__global__ __launch_bounds__(512) void scan_pass2(int* __restrict__ sums, int nb) {
    __shared__ int sc[512];
    int t = threadIdx.x;
    int v = (t < nb) ? sums[t] : 0;
    sc[t] = v; __syncthreads();
    for (int off = 1; off < 512; off <<= 1) {
        int x = (t >= off) ? sc[t - off] : 0;
        __syncthreads(); sc[t] += x; __syncthreads();
    }
    if (t < nb) sums[t] = sc[t] - v;     // exclusive
}

__global__ __launch_bounds__(256) void scan_pass3(const int* __restrict__ cnt,
                                                  const int* __restrict__ sums,
                                                  int* __restrict__ row_ptr) {
    __shared__ int sc[256];
    int b = blockIdx.x, t = threadIdx.x;
    int base = b * 1024 + t * 4;
    int e[4]; int v = 0;
    #pragma unroll
    for (int i = 0; i < 4; ++i) { int idx = base + i; e[i] = (idx < NSEG) ? cnt[idx] : 0; v += e[i]; }
    sc[t] = v; __syncthreads();
    for (int off = 1; off < 256; off <<= 1) {
        int x = (t >= off) ? sc[t - off] : 0;
        __syncthreads(); sc[t] += x; __syncthreads();
    }
    int run = sums[b] + (sc[t] - v);
    #pragma unroll
    for (int i = 0; i < 4; ++i) {
        int idx = base + i;
        if (idx < NSEG) row_ptr[idx] = run;
        run += e[i];
    }
    if (b == 0 && t == 0) row_ptr[NSEG] = N_EDGES;
}

// cnt doubles as the placement cursor (atomicSub); cnt is dead afterwards.
__global__ void place_edges(const int* __restrict__ src, const int* __restrict__ dst,
                            const int* __restrict__ et, const int* __restrict__ row_ptr,
                            int* __restrict__ cnt, int* __restrict__ sorted) {
    int e = blockIdx.x * 256 + threadIdx.x;
    if (e >= N_EDGES) return;
    int r = et[e];
    int key = dst[e] * N_REL + r;
    int old = atomicSub(&cnt[key], 1);
    int r0 = row_ptr[key];
    int c = row_ptr[key + 1] - r0;                 // |N_r(dst)| for this segment
    sorted[r0 + old - 1] = src[e] | (r << 17) | (c << 20);
}

// ---------------- weight pack: BT[col][k] bf16, col = r*O+o (r=8 -> root), zero-pad cols ----------------

__global__ void convert_weights(const float* __restrict__ W, const float* __restrict__ root,
                                ushort* __restrict__ BT, int K, int O, int NPAD) {
    int idx = blockIdx.x * 256 + threadIdx.x;
    if (idx >= NPAD * K) return;
    int col = idx / K, i = idx % K;
    float v = 0.0f;
    if (col < N_REL * O) {
        int r = col / O, o = col % O;
        v = W[((size_t)r * K + i) * O + o];
    } else if (col < (N_REL + 1) * O) {
        v = root[(size_t)i * O + (col - N_REL * O)];
    }
    BT[idx] = f2bf(v);
}

__global__ void f32_to_bf16(const float* __restrict__ in, ushort* __restrict__ out, int n4) {
    int i = blockIdx.x * 256 + threadIdx.x;
    if (i >= n4) return;
    float4 v = ((const float4*)in)[i];
    ushort4 s; s.x = f2bf(v.x); s.y = f2bf(v.y); s.z = f2bf(v.z); s.w = f2bf(v.w);
    ((ushort4*)out)[i] = s;
}

// ---------------- bf16 MFMA GEMM (round-0 proven structure + k-loop XOR chunk-swizzle) ----------------
// Epilogue: two-pass 32-row LDS transpose -> full-line 128 B coalesced stores (proven:
// direct 8 B row-strided stores regressed 96->128 us in round 2 via 4x L2 write
// transactions). K-loop LDS: rows are 64 B (4 chunks of 16 B); linear layout puts a
// 16-lane read group (fixed q) on only 2 of 8 bank-positions -> 8-way conflict (the
// 7.2M SQ_LDS_BANK_CONFLICT cycles). Fix per rule #21 (global_load_lds writes
// linearly): LDS slot (row r, chunk j) is loaded FROM global chunk j^((r>>1)&3), and
// the fragment read addresses slot q^((row>>1)&3). Involution on both sides ->
// bijective; 16-lane group now covers all 8 positions 2-way (free). Global staging
// still fetches whole 64 B row segments (chunks permuted within a line).
template<int K, int CTS, int NW>
__global__ __launch_bounds__(256)
void gemm_mfma(const ushort* __restrict__ A, const ushort* __restrict__ BT,
               ushort* __restrict__ Y) {
    // ---- swizzle: f -> (stripe y, col-tile ct) pinned to XCD f&7 ----
    const int f = blockIdx.x;
    const int g = f & 7, m = f >> 3;
    const int y = g + 8 * (m / CTS);
    const int ct = m % CTS;
    if (y >= NSTRIPE) return;               // uniform early-exit (before any barrier)
    const int row0 = y * 128;
    const int col0 = ct * 128;

    __shared__ ushort SMEM[9216];           // 18432 B: k-loop As|Bs (16 KB) / epilogue Ts
    ushort* As = SMEM;                      // 128*32 = 4096 ushorts
    ushort* Bs = SMEM + 4096;
    const int t = threadIdx.x;
    const int lane = t & 63;
    const int w = t >> 6;
    const int l16 = lane & 15, q = lane >> 4;
    const int wm = (w & 1) * 64, wn = (w >> 1) * 64;

    // staging: slot c (0..511) = 16B; row r = c>>2, chunk j = c&3. Wave w handles
    // slots [w*64, w*64+64) and [(w+4)*64, ...): LDS dst = wave-uniform base + lane*16.
    // Global source chunk is XOR-permuted so the swizzled read below finds its data.
    const int c0i = w * 64 + lane;
    const int c1i = c0i + 256;
    const int r0i = c0i >> 2, r1i = c1i >> 2;
    const int j0i = (c0i & 3) ^ ((r0i >> 1) & 3);
    const int j1i = (c1i & 3) ^ ((r1i >> 1) & 3);
    const size_t ga0 = (size_t)r0i * K + (size_t)j0i * 8;
    const size_t ga1 = (size_t)r1i * K + (size_t)j1i * 8;
    const ushort* Ab = A + (size_t)row0 * K;
    const ushort* Bb = BT + (size_t)col0 * K;
    ushort* lA0 = &As[w * 512];
    ushort* lA1 = &As[(w + 4) * 512];
    ushort* lB0 = &Bs[w * 512];
    ushort* lB1 = &Bs[(w + 4) * 512];

    // fragment-read chunk swizzle: row = wm|wn + i*16 + l16 -> (row>>1)&3 == (l16>>1)&3
    const int qx = (q ^ ((l16 >> 1) & 3)) * 8;

    f32x4 acc[4][4] = {};

    #pragma unroll
    for (int k0 = 0; k0 < K; k0 += 32) {
        __syncthreads();                    // previous iter's LDS reads done
        async16(Ab + k0 + ga0, lA0);
        async16(Ab + k0 + ga1, lA1);
        async16(Bb + k0 + ga0, lB0);
        async16(Bb + k0 + ga1, lB1);
        __syncthreads();                    // drains global_load_lds (vmcnt 0)
        bf16x8 a[4], b[4];
        #pragma unroll
        for (int i = 0; i < 4; ++i) {
            a[i] = *(const bf16x8*)&As[(wm + i * 16 + l16) * 32 + qx];
            b[i] = *(const bf16x8*)&Bs[(wn + i * 16 + l16) * 32 + qx];
        }
        #pragma unroll
        for (int i = 0; i < 4; ++i)
            #pragma unroll
            for (int j = 0; j < 4; ++j)
                acc[i][j] = __builtin_amdgcn_mfma_f32_16x16x32_bf16(a[i], b[j], acc[i][j], 0, 0, 0);
    }

    // ---- epilogue: two-pass transpose via wave-private LDS (32 rows x stride 72),
    // then full-line stores: 8 lanes cover 128 B of one row per instruction.
    __syncthreads();                        // k-loop LDS reads done; reuse SMEM as Ts
    ushort* Ts = &SMEM[w * 32 * 72];
    const int rr = lane >> 3;               // 0..7 row within 8-row group
    const int cc = (lane & 7) * 8;          // 16B chunk within row
    #pragma unroll
    for (int half = 0; half < 2; ++half) {
        // scatter: D mapping col=l16, row=q*4+reg (verified gfx950 layout)
        #pragma unroll
        for (int i = 0; i < 2; ++i)
            #pragma unroll
            for (int j = 0; j < 4; ++j)
                #pragma unroll
                for (int r = 0; r < 4; ++r)
                    Ts[(i * 16 + q * 4 + r) * 72 + j * 16 + l16] = f2bf(acc[half * 2 + i][j][r]);
        // gather+store (wave-private region; compiler orders LDS ops via lgkmcnt)
        #pragma unroll
        for (int p = 0; p < 4; ++p) {
            int row = p * 8 + rr;           // 0..31 local
            uint4 v = *(const uint4*)&Ts[row * 72 + cc];
            *(uint4*)(Y + (size_t)(row0 + wm + half * 32 + row) * NW + col0 + wn + cc) = v;
        }
    }
}

// ---------------- fused gather: out[d] = act( root + bias + sum_e w_e * Y[src_e, rel_e*O+c] ) ----------------
// dst-major sort: one contiguous edge run per dst; weight = 1/count decoded from the
// packed entry. 4-unrolled flat loop -> 4 independent metadata loads + 4 independent
// Y loads in flight.
template<int O>
__global__ __launch_bounds__(256)
void gather_kernel(const ushort* __restrict__ Y, int NW,
                   const int* __restrict__ row_ptr, const int* __restrict__ sorted,
                   const float* __restrict__ bias,
                   float* __restrict__ out_f32, ushort* __restrict__ out_bf16, int relu) {
    constexpr int TPN = O / 8;
    int d = blockIdx.x * (256 / TPN) + threadIdx.x / TPN;
    if (d >= N_NODES) return;
    int c0 = (threadIdx.x % TPN) * 8;
    int p0 = row_ptr[d * N_REL];
    int p1 = row_ptr[d * N_REL + N_REL];
    float sum[8] = {};
    add8(sum, *(const uint4*)(Y + (size_t)d * NW + N_REL * O + c0));   // root slice
    #pragma unroll
    for (int k = 0; k < 8; ++k) sum[k] += bias[c0 + k];
    const ushort* Yc = Y + c0;
    #define EDGE_LD(sx) (*(const uint4*)(Yc + (size_t)((sx) & 0x1FFFF) * NW + ((((sx) >> 17) & 7) * O)))
    #define EDGE_W(sx)  (1.0f / (float)((unsigned)(sx) >> 20))
    int e = p0;
    for (; e + 4 <= p1; e += 4) {
        int s0 = sorted[e], s1 = sorted[e + 1], s2 = sorted[e + 2], s3 = sorted[e + 3];
        uint4 v0 = EDGE_LD(s0);
        uint4 v1 = EDGE_LD(s1);
        uint4 v2 = EDGE_LD(s2);
        uint4 v3 = EDGE_LD(s3);
        fma8(sum, v0, EDGE_W(s0));
        fma8(sum, v1, EDGE_W(s1));
        fma8(sum, v2, EDGE_W(s2));
        fma8(sum, v3, EDGE_W(s3));
    }
    for (; e < p1; ++e) {
        int s = sorted[e];
        uint4 v = EDGE_LD(s);
        fma8(sum, v, EDGE_W(s));
    }
    #undef EDGE_LD
    #undef EDGE_W
    if (relu) {
        #pragma unroll
        for (int k = 0; k < 8; ++k) sum[k] = fmaxf(sum[k], 0.0f);
    }
    if (out_bf16) {
        ushort o[8];
        #pragma unroll
        for (int k = 0; k < 8; ++k) o[k] = f2bf(sum[k]);
        *(uint4*)(out_bf16 + (size_t)d * O + c0) = *(const uint4*)o;
    } else {
        float* p = out_f32 + (size_t)d * O + c0;
        *(float4*)p = make_float4(sum[0], sum[1], sum[2], sum[3]);
        *(float4*)(p + 4) = make_float4(sum[4], sum[5], sum[6], sum[7]);
    }
}

// ---------------- host side ----------------

extern "C" void kernel_launch(void* const* d_in, const int* in_sizes, int n_in,
                              void* d_out, int out_size, void* d_ws, size_t ws_size,
                              hipStream_t stream) {
    const float* x  = (const float*)d_in[0];
    const int*   ei = (const int*)d_in[1];
    const int*   et = (const int*)d_in[2];
    const float* W[4]  = {(const float*)d_in[3], (const float*)d_in[6], (const float*)d_in[9],  (const float*)d_in[12]};
    const float* RT[4] = {(const float*)d_in[4], (const float*)d_in[7], (const float*)d_in[10], (const float*)d_in[13]};
    const float* BI[4] = {(const float*)d_in[5], (const float*)d_in[8], (const float*)d_in[11], (const float*)d_in[14]};
    const int KS[4] = {128, 256, 256, 256};
    const int NP[4] = {2304, 2304, 2304, 640};   // packed+padded BT rows (= Y width)
    const int* src = ei;
    const int* dst = ei + N_EDGES;

    // ---- workspace carve-up (footprint <= proven round-0 layout) ----
    char* ws = (char*)d_ws;
    size_t off = 0;
    auto take = [&](size_t bytes) -> char* {
        char* p = ws + off;
        off = (off + bytes + 255) & ~(size_t)255;
        return p;
    };
    int* row_ptr    = (int*)take((size_t)(NSEG + 1) * 4);
    int* sorted     = (int*)take((size_t)N_EDGES * 4);
    ushort* BTp[4];
    for (int l = 0; l < 4; ++l) BTp[l] = (ushort*)take((size_t)NP[l] * KS[l] * 2);
    ushort* hb = (ushort*)take((size_t)N_PAD * 256 * 2);
    ushort* Yb = (ushort*)take((size_t)N_PAD * 2304 * 2);
    // cnt + sums alias the head of Yb: dead before the first GEMM writes Yb
    // (strict stream order), saves their 1.6 MB from the footprint.
    int* cnt  = (int*)Yb;
    int* sums = (int*)((char*)Yb + (size_t)NSEG * 4);

    // ---- edge preprocessing (once per call) ----
    hipMemsetAsync(cnt, 0, (size_t)NSEG * 4, stream);
    count_edges<<<(N_EDGES + 255) / 256, 256, 0, stream>>>(dst, et, cnt);
    scan_pass1<<<SCAN_NB, 256, 0, stream>>>(cnt, sums);
    scan_pass2<<<1, 512, 0, stream>>>(sums, SCAN_NB);
    scan_pass3<<<SCAN_NB, 256, 0, stream>>>(cnt, sums, row_ptr);
    place_edges<<<(N_EDGES + 255) / 256, 256, 0, stream>>>(src, dst, et, row_ptr, cnt, sorted);

    // ---- weight pack ----
    for (int l = 0; l < 4; ++l) {
        int n = NP[l] * KS[l];
        convert_weights<<<(n + 255) / 256, 256, 0, stream>>>(W[l], RT[l], BTp[l], KS[l],
                                                             l == 3 ? 64 : 256, NP[l]);
    }

    // ---- input to bf16 ----
    f32_to_bf16<<<(N_NODES * 128 / 4 + 255) / 256, 256, 0, stream>>>(x, hb, N_NODES * 128 / 4);

    // ---- 4 layers: XCD-swizzled GEMM + fused gather ----
    const int G18 = 8 * SPX * 18;   // 7056
    const int G5  = 8 * SPX * 5;    // 1960
    gemm_mfma<128, 18, 2304><<<G18, 256, 0, stream>>>(hb, BTp[0], Yb);
    gather_kernel<256><<<dim3((N_NODES + 7) / 8), 256, 0, stream>>>(
        Yb, 2304, row_ptr, sorted, BI[0], nullptr, hb, 1);

    gemm_mfma<256, 18, 2304><<<G18, 256, 0, stream>>>(hb, BTp[1], Yb);
    gather_kernel<256><<<dim3((N_NODES + 7) / 8), 256, 0, stream>>>(
        Yb, 2304, row_ptr, sorted, BI[1], nullptr, hb, 1);

    gemm_mfma<256, 18, 2304><<<G18, 256, 0, stream>>>(hb, BTp[2], Yb);
    gather_kernel<256><<<dim3((N_NODES + 7) / 8), 256, 0, stream>>>(
        Yb, 2304, row_ptr, sorted, BI[2], nullptr, hb, 1);

    gemm_mfma<256, 5, 640><<<G5, 256, 0, stream>>>(hb, BTp[3], Yb);
    gather_kernel<64><<<dim3((N_NODES + 31) / 32), 256, 0, stream>>>(
        Yb, 640, row_ptr, sorted, BI[3], (float*)d_out, nullptr, 0);
}

// Round 4
// 669.985 us; speedup vs baseline: 1.1591x; 1.0015x over previous
//
#include <hip/hip_runtime.h>

#define N_NODES 50000
#define N_PAD   50048          // 391 * 128
#define N_EDGES 800000
#define N_REL   8
#define NSEG    (N_REL * N_NODES)      // 400000
#define SCAN_NB 391                    // ceil(NSEG / 1024)
#define NSTRIPE 391                    // 128-row stripes
#define SPX     49                     // ceil(391/8) stripes per XCD

typedef short bf16x8 __attribute__((ext_vector_type(8)));
typedef float f32x4  __attribute__((ext_vector_type(4)));

__device__ __forceinline__ ushort f2bf(float f) {
    union { float f; unsigned u; } c; c.f = f;
    unsigned u = c.u + 0x7fffu + ((c.u >> 16) & 1u);   // RNE
    return (ushort)(u >> 16);
}
__device__ __forceinline__ void add8(float* s, uint4 v) {
    unsigned u[4] = {v.x, v.y, v.z, v.w};
    #pragma unroll
    for (int k = 0; k < 4; ++k) {
        s[2 * k]     += __uint_as_float(u[k] << 16);
        s[2 * k + 1] += __uint_as_float(u[k] & 0xffff0000u);
    }
}
__device__ __forceinline__ void fma8(float* s, uint4 v, float w) {
    unsigned u[4] = {v.x, v.y, v.z, v.w};
    #pragma unroll
    for (int k = 0; k < 4; ++k) {
        s[2 * k]     = fmaf(__uint_as_float(u[k] << 16),        w, s[2 * k]);
        s[2 * k + 1] = fmaf(__uint_as_float(u[k] & 0xffff0000u), w, s[2 * k + 1]);
    }
}
__device__ __forceinline__ void async16(const ushort* g, ushort* l) {
    __builtin_amdgcn_global_load_lds((const __attribute__((address_space(1))) void*)g,
                                     (__attribute__((address_space(3))) void*)l, 16, 0, 0);
}

// ---------------- edge preprocessing: counting sort by (dst*R + rel) ----------------
// dst-major key: each dst owns ONE contiguous run of ~16 edges -> gather is a single
// flat loop with high MLP instead of 8 trip-2 loops with serial dependent loads.
// sorted[pos] packs {src:17b | rel:3b | segment_count:12b} in one int (4 B/edge).

__global__ void count_edges(const int* __restrict__ dst, const int* __restrict__ et,
                            int* __restrict__ cnt) {
    int e = blockIdx.x * 256 + threadIdx.x;
    if (e < N_EDGES) atomicAdd(&cnt[dst[e] * N_REL + et[e]], 1);
}

__global__ __launch_bounds__(256) void scan_pass1(const int* __restrict__ cnt,
                                                  int* __restrict__ sums) {
    __shared__ int sc[256];
    int b = blockIdx.x, t = threadIdx.x;
    int base = b * 1024 + t * 4;
    int v = 0;
    #pragma unroll
    for (int i = 0; i < 4; ++i) { int idx = base + i; if (idx < NSEG) v += cnt[idx]; }
    sc[t] = v; __syncthreads();
    for (int off = 1; off < 256; off <<= 1) {
        int x = (t >= off) ? sc[t - off] : 0;
        __syncthreads(); sc[t] += x; __syncthreads();
    }
    if (t == 255) sums[b] = sc[255];
}

__global__ __launch_bounds__(512) void scan_pass2(int* __restrict__ sums, int nb) {
    __shared__ int sc[512];
    int t = threadIdx.x;
    int v = (t < nb) ? sums[t] : 0;
    sc[t] = v; __syncthreads();
    for (int off = 1; off < 512; off <<= 1) {
        int x = (t >= off) ? sc[t - off] : 0;
        __syncthreads(); sc[t] += x; __syncthreads();
    }
    if (t < nb) sums[t] = sc[t] - v;     // exclusive
}

__global__ __launch_bounds__(256) void scan_pass3(const int* __restrict__ cnt,
                                                  const int* __restrict__ sums,
                                                  int* __restrict__ row_ptr) {
    __shared__ int sc[256];
    int b = blockIdx.x, t = threadIdx.x;
    int base = b * 1024 + t * 4;
    int e[4]; int v = 0;
    #pragma unroll
    for (int i = 0; i < 4; ++i) { int idx = base + i; e[i] = (idx < NSEG) ? cnt[idx] : 0; v += e[i]; }
    sc[t] = v; __syncthreads();
    for (int off = 1; off < 256; off <<= 1) {
        int x = (t >= off) ? sc[t - off] : 0;
        __syncthreads(); sc[t] += x; __syncthreads();
    }
    int run = sums[b] + (sc[t] - v);
    #pragma unroll
    for (int i = 0; i < 4; ++i) {
        int idx = base + i;
        if (idx < NSEG) row_ptr[idx] = run;
        run += e[i];
    }
    if (b == 0 && t == 0) row_ptr[NSEG] = N_EDGES;
}

// cnt doubles as the placement cursor (atomicSub); cnt is dead afterwards.
__global__ void place_edges(const int* __restrict__ src, const int* __restrict__ dst,
                            const int* __restrict__ et, const int* __restrict__ row_ptr,
                            int* __restrict__ cnt, int* __restrict__ sorted) {
    int e = blockIdx.x * 256 + threadIdx.x;
    if (e >= N_EDGES) return;
    int r = et[e];
    int key = dst[e] * N_REL + r;
    int old = atomicSub(&cnt[key], 1);
    int r0 = row_ptr[key];
    int c = row_ptr[key + 1] - r0;                 // |N_r(dst)| for this segment
    sorted[r0 + old - 1] = src[e] | (r << 17) | (c << 20);
}

// ---------------- weight pack: BT[col][k] bf16, col = r*O+o (r=8 -> root), zero-pad cols ----------------

__global__ void convert_weights(const float* __restrict__ W, const float* __restrict__ root,
                                ushort* __restrict__ BT, int K, int O, int NPAD) {
    int idx = blockIdx.x * 256 + threadIdx.x;
    if (idx >= NPAD * K) return;
    int col = idx / K, i = idx % K;
    float v = 0.0f;
    if (col < N_REL * O) {
        int r = col / O, o = col % O;
        v = W[((size_t)r * K + i) * O + o];
    } else if (col < (N_REL + 1) * O) {
        v = root[(size_t)i * O + (col - N_REL * O)];
    }
    BT[idx] = f2bf(v);
}

__global__ void f32_to_bf16(const float* __restrict__ in, ushort* __restrict__ out, int n4) {
    int i = blockIdx.x * 256 + threadIdx.x;
    if (i >= n4) return;
    float4 v = ((const float4*)in)[i];
    ushort4 s; s.x = f2bf(v.x); s.y = f2bf(v.y); s.z = f2bf(v.z); s.w = f2bf(v.w);
    ((ushort4*)out)[i] = s;
}

// ---------------- bf16 MFMA GEMM: 2-phase double-buffered k-loop (T3 minimum) ----------------
// Round-3 post-mortem: killing 6.3M bank-conflict cycles changed nothing -> the k-loop
// was latency/sync-bound, not conflict-bound. The 1-phase structure (stage -> drain ->
// compute, 2 barriers/step) serializes ~300-900 cy of global_load_lds latency against
// ~620 cy of MFMA at only ~2.3 blocks/CU. This version: double 16 KB LDS buffers;
// per step ISSUE next tile's loads, THEN compute current tile, THEN one __syncthreads
// (its implicit vmcnt(0) now waits on loads that had the whole MFMA phase in flight).
// Hazards: STAGE(s+1) writes buf (s+1)&1 while COMPUTE(s) reads buf s&1 (disjoint);
// buf reuse guarded by the per-step barrier; epilogue Ts aliases SMEM head strictly
// after the final barrier. Loop fully unrolled -> buffer choice is compile-time.
template<int K, int CTS, int NW>
__global__ __launch_bounds__(256)
void gemm_mfma(const ushort* __restrict__ A, const ushort* __restrict__ BT,
               ushort* __restrict__ Y) {
    // ---- swizzle: f -> (stripe y, col-tile ct) pinned to XCD f&7 ----
    const int f = blockIdx.x;
    const int g = f & 7, m = f >> 3;
    const int y = g + 8 * (m / CTS);
    const int ct = m % CTS;
    if (y >= NSTRIPE) return;               // uniform early-exit (before any barrier)
    const int row0 = y * 128;
    const int col0 = ct * 128;

    __shared__ ushort SMEM[16384];          // 32 KB: 2 x (As|Bs 16 KB); epilogue Ts aliases head
    const int t = threadIdx.x;
    const int lane = t & 63;
    const int w = t >> 6;
    const int l16 = lane & 15, q = lane >> 4;
    const int wm = (w & 1) * 64, wn = (w >> 1) * 64;

    // staging: slot c (0..511) = 16B; row r = c>>2, chunk j = c&3. Wave w handles
    // slots [w*64, w*64+64) and [(w+4)*64, ...): LDS dst = wave-uniform base + lane*16.
    // Global source chunk XOR-permuted (rule #21) so the swizzled read finds its data.
    const int c0i = w * 64 + lane;
    const int c1i = c0i + 256;
    const int r0i = c0i >> 2, r1i = c1i >> 2;
    const int j0i = (c0i & 3) ^ ((r0i >> 1) & 3);
    const int j1i = (c1i & 3) ^ ((r1i >> 1) & 3);
    const size_t ga0 = (size_t)r0i * K + (size_t)j0i * 8;
    const size_t ga1 = (size_t)r1i * K + (size_t)j1i * 8;
    const ushort* Ab = A + (size_t)row0 * K;
    const ushort* Bb = BT + (size_t)col0 * K;

    // fragment-read chunk swizzle: row = wm|wn + i*16 + l16 -> (row>>1)&3 == (l16>>1)&3
    const int qx = (q ^ ((l16 >> 1) & 3)) * 8;

    f32x4 acc[4][4] = {};

    // buffer b: As at SMEM + b*8192, Bs at +4096
    auto STAGE = [&](int b, int k0) {
        ushort* As = SMEM + b * 8192;
        ushort* Bs = As + 4096;
        async16(Ab + k0 + ga0, &As[w * 512]);
        async16(Ab + k0 + ga1, &As[(w + 4) * 512]);
        async16(Bb + k0 + ga0, &Bs[w * 512]);
        async16(Bb + k0 + ga1, &Bs[(w + 4) * 512]);
    };
    auto COMPUTE = [&](int b) {
        ushort* As = SMEM + b * 8192;
        ushort* Bs = As + 4096;
        bf16x8 a[4], bb[4];
        #pragma unroll
        for (int i = 0; i < 4; ++i) {
            a[i]  = *(const bf16x8*)&As[(wm + i * 16 + l16) * 32 + qx];
            bb[i] = *(const bf16x8*)&Bs[(wn + i * 16 + l16) * 32 + qx];
        }
        #pragma unroll
        for (int i = 0; i < 4; ++i)
            #pragma unroll
            for (int j = 0; j < 4; ++j)
                acc[i][j] = __builtin_amdgcn_mfma_f32_16x16x32_bf16(a[i], bb[j], acc[i][j], 0, 0, 0);
    };

    constexpr int NSTEP = K / 32;
    STAGE(0, 0);
    __syncthreads();                        // prologue drain (first tile staged)
    #pragma unroll
    for (int s = 0; s < NSTEP; ++s) {
        if (s + 1 < NSTEP) STAGE((s + 1) & 1, 32 * (s + 1));   // prefetch next tile
        COMPUTE(s & 1);                                         // compute current
        __syncthreads();   // implicit vmcnt(0): next tile landed (hidden under MFMA)
    }

    // ---- epilogue: two-pass transpose via wave-private LDS (32 rows x stride 72),
    // then full-line stores: 8 lanes cover 128 B of one row per instruction.
    // (final k-loop barrier above guards the SMEM alias)
    ushort* Ts = &SMEM[w * 32 * 72];
    const int rr = lane >> 3;               // 0..7 row within 8-row group
    const int cc = (lane & 7) * 8;          // 16B chunk within row
    #pragma unroll
    for (int half = 0; half < 2; ++half) {
        // scatter: D mapping col=l16, row=q*4+reg (verified gfx950 layout)
        #pragma unroll
        for (int i = 0; i < 2; ++i)
            #pragma unroll
            for (int j = 0; j < 4; ++j)
                #pragma unroll
                for (int r = 0; r < 4; ++r)
                    Ts[(i * 16 + q * 4 + r) * 72 + j * 16 + l16] = f2bf(acc[half * 2 + i][j][r]);
        // gather+store (wave-private region; compiler orders LDS ops via lgkmcnt)
        #pragma unroll
        for (int p = 0; p < 4; ++p) {
            int row = p * 8 + rr;           // 0..31 local
            uint4 v = *(const uint4*)&Ts[row * 72 + cc];
            *(uint4*)(Y + (size_t)(row0 + wm + half * 32 + row) * NW + col0 + wn + cc) = v;
        }
    }
}

// ---------------- fused gather: out[d] = act( root + bias + sum_e w_e * Y[src_e, rel_e*O+c] ) ----------------
// dst-major sort: one contiguous edge run per dst; weight = 1/count decoded from the
// packed entry. 4-unrolled flat loop -> 4 independent metadata loads + 4 independent
// Y loads in flight.
template<int O>
__global__ __launch_bounds__(256)
void gather_kernel(const ushort* __restrict__ Y, int NW,
                   const int* __restrict__ row_ptr, const int* __restrict__ sorted,
                   const float* __restrict__ bias,
                   float* __restrict__ out_f32, ushort* __restrict__ out_bf16, int relu) {
    constexpr int TPN = O / 8;
    int d = blockIdx.x * (256 / TPN) + threadIdx.x / TPN;
    if (d >= N_NODES) return;
    int c0 = (threadIdx.x % TPN) * 8;
    int p0 = row_ptr[d * N_REL];
    int p1 = row_ptr[d * N_REL + N_REL];
    float sum[8] = {};
    add8(sum, *(const uint4*)(Y + (size_t)d * NW + N_REL * O + c0));   // root slice
    #pragma unroll
    for (int k = 0; k < 8; ++k) sum[k] += bias[c0 + k];
    const ushort* Yc = Y + c0;
    #define EDGE_LD(sx) (*(const uint4*)(Yc + (size_t)((sx) & 0x1FFFF) * NW + ((((sx) >> 17) & 7) * O)))
    #define EDGE_W(sx)  (1.0f / (float)((unsigned)(sx) >> 20))
    int e = p0;
    for (; e + 4 <= p1; e += 4) {
        int s0 = sorted[e], s1 = sorted[e + 1], s2 = sorted[e + 2], s3 = sorted[e + 3];
        uint4 v0 = EDGE_LD(s0);
        uint4 v1 = EDGE_LD(s1);
        uint4 v2 = EDGE_LD(s2);
        uint4 v3 = EDGE_LD(s3);
        fma8(sum, v0, EDGE_W(s0));
        fma8(sum, v1, EDGE_W(s1));
        fma8(sum, v2, EDGE_W(s2));
        fma8(sum, v3, EDGE_W(s3));
    }
    for (; e < p1; ++e) {
        int s = sorted[e];
        uint4 v = EDGE_LD(s);
        fma8(sum, v, EDGE_W(s));
    }
    #undef EDGE_LD
    #undef EDGE_W
    if (relu) {
        #pragma unroll
        for (int k = 0; k < 8; ++k) sum[k] = fmaxf(sum[k], 0.0f);
    }
    if (out_bf16) {
        ushort o[8];
        #pragma unroll
        for (int k = 0; k < 8; ++k) o[k] = f2bf(sum[k]);
        *(uint4*)(out_bf16 + (size_t)d * O + c0) = *(const uint4*)o;
    } else {
        float* p = out_f32 + (size_t)d * O + c0;
        *(float4*)p = make_float4(sum[0], sum[1], sum[2], sum[3]);
        *(float4*)(p + 4) = make_float4(sum[4], sum[5], sum[6], sum[7]);
    }
}

// ---------------- host side ----------------

extern "C" void kernel_launch(void* const* d_in, const int* in_sizes, int n_in,
                              void* d_out, int out_size, void* d_ws, size_t ws_size,
                              hipStream_t stream) {
    const float* x  = (const float*)d_in[0];
    const int*   ei = (const int*)d_in[1];
    const int*   et = (const int*)d_in[2];
    const float* W[4]  = {(const float*)d_in[3], (const float*)d_in[6], (const float*)d_in[9],  (const float*)d_in[12]};
    const float* RT[4] = {(const float*)d_in[4], (const float*)d_in[7], (const float*)d_in[10], (const float*)d_in[13]};
    const float* BI[4] = {(const float*)d_in[5], (const float*)d_in[8], (const float*)d_in[11], (const float*)d_in[14]};
    const int KS[4] = {128, 256, 256, 256};
    const int NP[4] = {2304, 2304, 2304, 640};   // packed+padded BT rows (= Y width)
    const int* src = ei;
    const int* dst = ei + N_EDGES;

    // ---- workspace carve-up (footprint <= proven round-0 layout) ----
    char* ws = (char*)d_ws;
    size_t off = 0;
    auto take = [&](size_t bytes) -> char* {
        char* p = ws + off;
        off = (off + bytes + 255) & ~(size_t)255;
        return p;
    };
    int* row_ptr    = (int*)take((size_t)(NSEG + 1) * 4);
    int* sorted     = (int*)take((size_t)N_EDGES * 4);
    ushort* BTp[4];
    for (int l = 0; l < 4; ++l) BTp[l] = (ushort*)take((size_t)NP[l] * KS[l] * 2);
    ushort* hb = (ushort*)take((size_t)N_PAD * 256 * 2);
    ushort* Yb = (ushort*)take((size_t)N_PAD * 2304 * 2);
    // cnt + sums alias the head of Yb: dead before the first GEMM writes Yb
    // (strict stream order), saves their 1.6 MB from the footprint.
    int* cnt  = (int*)Yb;
    int* sums = (int*)((char*)Yb + (size_t)NSEG * 4);

    // ---- edge preprocessing (once per call) ----
    hipMemsetAsync(cnt, 0, (size_t)NSEG * 4, stream);
    count_edges<<<(N_EDGES + 255) / 256, 256, 0, stream>>>(dst, et, cnt);
    scan_pass1<<<SCAN_NB, 256, 0, stream>>>(cnt, sums);
    scan_pass2<<<1, 512, 0, stream>>>(sums, SCAN_NB);
    scan_pass3<<<SCAN_NB, 256, 0, stream>>>(cnt, sums, row_ptr);
    place_edges<<<(N_EDGES + 255) / 256, 256, 0, stream>>>(src, dst, et, row_ptr, cnt, sorted);

    // ---- weight pack ----
    for (int l = 0; l < 4; ++l) {
        int n = NP[l] * KS[l];
        convert_weights<<<(n + 255) / 256, 256, 0, stream>>>(W[l], RT[l], BTp[l], KS[l],
                                                             l == 3 ? 64 : 256, NP[l]);
    }

    // ---- input to bf16 ----
    f32_to_bf16<<<(N_NODES * 128 / 4 + 255) / 256, 256, 0, stream>>>(x, hb, N_NODES * 128 / 4);

    // ---- 4 layers: XCD-swizzled GEMM + fused gather ----
    const int G18 = 8 * SPX * 18;   // 7056
    const int G5  = 8 * SPX * 5;    // 1960
    gemm_mfma<128, 18, 2304><<<G18, 256, 0, stream>>>(hb, BTp[0], Yb);
    gather_kernel<256><<<dim3((N_NODES + 7) / 8), 256, 0, stream>>>(
        Yb, 2304, row_ptr, sorted, BI[0], nullptr, hb, 1);

    gemm_mfma<256, 18, 2304><<<G18, 256, 0, stream>>>(hb, BTp[1], Yb);
    gather_kernel<256><<<dim3((N_NODES + 7) / 8), 256, 0, stream>>>(
        Yb, 2304, row_ptr, sorted, BI[1], nullptr, hb, 1);

    gemm_mfma<256, 18, 2304><<<G18, 256, 0, stream>>>(hb, BTp[2], Yb);
    gather_kernel<256><<<dim3((N_NODES + 7) / 8), 256, 0, stream>>>(
        Yb, 2304, row_ptr, sorted, BI[2], nullptr, hb, 1);

    gemm_mfma<256, 5, 640><<<G5, 256, 0, stream>>>(hb, BTp[3], Yb);
    gather_kernel<64><<<dim3((N_NODES + 31) / 32), 256, 0, stream>>>(
        Yb, 640, row_ptr, sorted, BI[3], (float*)d_out, nullptr, 0);
}